// Round 2
// baseline (9311.475 us; speedup 1.0000x reference)
//
#include <hip/hip_runtime.h>
#include <hip/hip_bf16.h>

// All float tensors are fp32 (per reference: jnp.float32); idx is int32.
// Output is fp32 logits [2048, 32000].

// ---------------------------------------------------------------------------
// Embedding gather: x[t,:] = wte[idx[t],:]
// ---------------------------------------------------------------------------
__global__ void embed_kernel(const int* __restrict__ idx,
                             const float* __restrict__ wte,
                             float* __restrict__ x) {
    const int t = blockIdx.x;
    const int row = idx[t];
    const float* w = wte + (size_t)row * 768;
    float* o = x + (size_t)t * 768;
    for (int d = threadIdx.x; d < 768; d += 256) o[d] = w[d];
}

// ---------------------------------------------------------------------------
// LayerNorm (no bias): out = (x - mu) * rsqrt(var + eps) * w      D = 768
// One block (256 thr) per row; each thread owns 3 elements.
// ---------------------------------------------------------------------------
__global__ __launch_bounds__(256) void ln_kernel(const float* __restrict__ x,
                                                 const float* __restrict__ w,
                                                 float* __restrict__ out) {
    const int t = blockIdx.x, tid = threadIdx.x;
    __shared__ float red[256];
    const float* xr = x + (size_t)t * 768;
    const float v0 = xr[tid], v1 = xr[tid + 256], v2 = xr[tid + 512];
    red[tid] = v0 + v1 + v2;
    __syncthreads();
    for (int s = 128; s > 0; s >>= 1) {
        if (tid < s) red[tid] += red[tid + s];
        __syncthreads();
    }
    const float mu = red[0] * (1.0f / 768.0f);
    __syncthreads();
    const float d0 = v0 - mu, d1 = v1 - mu, d2 = v2 - mu;
    red[tid] = d0 * d0 + d1 * d1 + d2 * d2;
    __syncthreads();
    for (int s = 128; s > 0; s >>= 1) {
        if (tid < s) red[tid] += red[tid + s];
        __syncthreads();
    }
    const float rstd = rsqrtf(red[0] * (1.0f / 768.0f) + 1e-5f);
    float* orow = out + (size_t)t * 768;
    orow[tid]       = d0 * rstd * w[tid];
    orow[tid + 256] = d1 * rstd * w[tid + 256];
    orow[tid + 512] = d2 * rstd * w[tid + 512];
}

// ---------------------------------------------------------------------------
// RoPE in-place on Q and K halves of qkv [T, 2304].
// HD=64; pair (i, i+32), angle = t * 10000^(-i/32).
// Block = (t, h), 64 threads: tid<32 -> Q pair i=tid; tid>=32 -> K pair.
// ---------------------------------------------------------------------------
__global__ void rope_kernel(float* __restrict__ qkv) {
    const int t = blockIdx.x, h = blockIdx.y;
    const int tid = threadIdx.x;
    const int i = tid & 31;
    const int which = tid >> 5;  // 0 = Q, 1 = K
    float* base = qkv + (size_t)t * 2304 + which * 768 + h * 64;
    const float inv_freq = __powf(10000.0f, -(float)i * (1.0f / 32.0f));
    const float ang = (float)t * inv_freq;
    const float s = sinf(ang), c = cosf(ang);
    const float x1 = base[i], x2 = base[i + 32];
    base[i]      = x1 * c - x2 * s;
    base[i + 32] = x1 * s + x2 * c;
}

// ---------------------------------------------------------------------------
// Causal attention, one block (256 thr) per (query q, head h).
// Scores row (<=2048 fp32) lives in LDS; block softmax; coalesced PV.
// qkv: [T, 2304] fp32 (Q|K|V), y: [T, 768] fp32 (head-major)
// ---------------------------------------------------------------------------
__global__ __launch_bounds__(256) void attn_kernel(const float* __restrict__ qkv,
                                                   float* __restrict__ y) {
    const int q = blockIdx.x, h = blockIdx.y;
    const int tid = threadIdx.x;
    __shared__ float qs[64];
    __shared__ float sc[2048];
    __shared__ float red[256];
    const int nk = q + 1;

    if (tid < 64) qs[tid] = qkv[(size_t)q * 2304 + h * 64 + tid];
    __syncthreads();

    // scores
    float lmax = -1e30f;
    for (int k = tid; k < nk; k += 256) {
        const float* Kp = qkv + (size_t)k * 2304 + 768 + h * 64;
        float d = 0.0f;
        #pragma unroll
        for (int i = 0; i < 64; i += 4) {
            const float4 kv = *(const float4*)(Kp + i);
            d += qs[i] * kv.x + qs[i + 1] * kv.y + qs[i + 2] * kv.z + qs[i + 3] * kv.w;
        }
        d *= 0.125f;  // 1/sqrt(64)
        sc[k] = d;
        lmax = fmaxf(lmax, d);
    }
    red[tid] = lmax;
    __syncthreads();
    for (int s = 128; s > 0; s >>= 1) {
        if (tid < s) red[tid] = fmaxf(red[tid], red[tid + s]);
        __syncthreads();
    }
    const float mx = red[0];
    __syncthreads();

    float lsum = 0.0f;
    for (int k = tid; k < nk; k += 256) {
        const float e = expf(sc[k] - mx);
        sc[k] = e;
        lsum += e;
    }
    red[tid] = lsum;
    __syncthreads();
    for (int s = 128; s > 0; s >>= 1) {
        if (tid < s) red[tid] += red[tid + s];
        __syncthreads();
    }
    const float inv = 1.0f / red[0];
    __syncthreads();

    // PV: threads = (d in 0..63) x (chunk c in 0..3); V[k,d] coalesced over d
    const int d = tid & 63, c = tid >> 6;
    float o = 0.0f;
    for (int k = c; k < nk; k += 4) {
        o += sc[k] * qkv[(size_t)k * 2304 + 1536 + h * 64 + d];
    }
    red[tid] = o;
    __syncthreads();
    if (c == 0) {
        const float ov = red[d] + red[d + 64] + red[d + 128] + red[d + 192];
        y[(size_t)q * 768 + h * 64 + d] = ov * inv;
    }
}

// ---------------------------------------------------------------------------
// NT GEMM: C[M,N] = A[M,K] * B[N,K]^T  (all fp32) with fused epilogue.
// Requires M,N % 64 == 0, K % 32 == 0 (true for all shapes here).
// FLAGS: 1=bias, 2=residual (result += existing C), 4=exact GELU
// Tile 64x64, BK=32, 256 threads, 4x4 micro-tile per thread.
// ---------------------------------------------------------------------------
template <int FLAGS>
__global__ __launch_bounds__(256) void gemm_nt(const float* __restrict__ A,
                                               const float* __restrict__ B,
                                               const float* __restrict__ bias,
                                               float* __restrict__ C,
                                               int M, int N, int K) {
    constexpr bool HAS_BIAS = (FLAGS & 1) != 0;
    constexpr bool HAS_RES  = (FLAGS & 2) != 0;
    constexpr bool HAS_GELU = (FLAGS & 4) != 0;

    __shared__ float As[32][64];
    __shared__ float Bs[32][64];

    const int tid = threadIdx.x;
    const int bm = blockIdx.y * 64, bn = blockIdx.x * 64;
    const int lr = tid >> 3;         // 0..31, loader row (2 rows per thread)
    const int lk = (tid & 7) << 2;   // 0..28, loader k offset (x4)
    const int tx = tid & 15, ty = tid >> 4;

    float acc[4][4] = {{0.0f}};

    for (int k0 = 0; k0 < K; k0 += 32) {
        #pragma unroll
        for (int r = lr; r < 64; r += 32) {
            const float4 av = *(const float4*)(A + (size_t)(bm + r) * K + (k0 + lk));
            As[lk + 0][r] = av.x; As[lk + 1][r] = av.y;
            As[lk + 2][r] = av.z; As[lk + 3][r] = av.w;
            const float4 bv = *(const float4*)(B + (size_t)(bn + r) * K + (k0 + lk));
            Bs[lk + 0][r] = bv.x; Bs[lk + 1][r] = bv.y;
            Bs[lk + 2][r] = bv.z; Bs[lk + 3][r] = bv.w;
        }
        __syncthreads();
        #pragma unroll
        for (int k = 0; k < 32; ++k) {
            float a[4], b[4];
            #pragma unroll
            for (int i = 0; i < 4; ++i) a[i] = As[k][ty * 4 + i];
            #pragma unroll
            for (int j = 0; j < 4; ++j) b[j] = Bs[k][tx * 4 + j];
            #pragma unroll
            for (int i = 0; i < 4; ++i)
                #pragma unroll
                for (int j = 0; j < 4; ++j) acc[i][j] += a[i] * b[j];
        }
        __syncthreads();
    }

    #pragma unroll
    for (int i = 0; i < 4; ++i) {
        const int row = bm + ty * 4 + i;
        #pragma unroll
        for (int j = 0; j < 4; ++j) {
            const int col = bn + tx * 4 + j;
            float v = acc[i][j];
            if constexpr (HAS_BIAS) v += bias[col];
            if constexpr (HAS_GELU) v = 0.5f * v * (1.0f + erff(v * 0.70710678118654752f));
            const size_t off = (size_t)row * N + col;
            if constexpr (HAS_RES) v += C[off];
            C[off] = v;
        }
    }
}

// ---------------------------------------------------------------------------
// Host launch
// ---------------------------------------------------------------------------
extern "C" void kernel_launch(void* const* d_in, const int* in_sizes, int n_in,
                              void* d_out, int out_size, void* d_ws, size_t ws_size,
                              hipStream_t stream) {
    const int T = 2048, D = 768, NH = 12, L = 4, V = 32000;
    const int D3 = 3 * D, D4 = 4 * D;

    const int*   idx        = (const int*)d_in[0];
    const float* wte        = (const float*)d_in[1];
    const float* ln1_w      = (const float*)d_in[2];
    const float* attn_w     = (const float*)d_in[3];
    const float* attnproj_w = (const float*)d_in[4];
    const float* ln2_w      = (const float*)d_in[5];
    const float* fc_w       = (const float*)d_in[6];
    const float* fc_b       = (const float*)d_in[7];
    const float* proj_w     = (const float*)d_in[8];
    const float* proj_b     = (const float*)d_in[9];
    const float* lnf_w      = (const float*)d_in[10];
    const float* unemb_b    = (const float*)d_in[11];
    float* out = (float*)d_out;

    // Workspace layout (fp32):
    //   X   : [T, D]    residual stream           @ 0        (6.3 MB)
    //   H   : [T, D]    LN out / attn out         @ 6.3 MB   (6.3 MB)
    //   QKV : [T, 3D]   qkv, reused as M [T, 4D]  @ 12.6 MB  (25.2 MB)
    // Peak: ~37.8 MB
    char* ws = (char*)d_ws;
    float* X   = (float*)ws;
    float* H   = (float*)(ws + (size_t)T * D * 4);
    float* QKV = (float*)(ws + (size_t)2 * T * D * 4);
    float* Mb  = QKV;

    embed_kernel<<<T, 256, 0, stream>>>(idx, wte, X);

    for (int l = 0; l < L; ++l) {
        // h = LN1(x)
        ln_kernel<<<T, 256, 0, stream>>>(X, ln1_w + (size_t)l * D, H);
        // qkv = h @ attn_w^T
        gemm_nt<0><<<dim3(D3 / 64, T / 64), 256, 0, stream>>>(
            H, attn_w + (size_t)l * D3 * D, nullptr, QKV, T, D3, D);
        // RoPE on q, k
        rope_kernel<<<dim3(T, NH), 64, 0, stream>>>(QKV);
        // y = softmax(qk^T) v   (into H; h no longer needed)
        attn_kernel<<<dim3(T, NH), 256, 0, stream>>>(QKV, H);
        // x += y @ attnproj_w^T
        gemm_nt<2><<<dim3(D / 64, T / 64), 256, 0, stream>>>(
            H, attnproj_w + (size_t)l * D * D, nullptr, X, T, D, D);
        // h = LN2(x)
        ln_kernel<<<T, 256, 0, stream>>>(X, ln2_w + (size_t)l * D, H);
        // m = gelu(h @ fc_w^T + fc_b)
        gemm_nt<5><<<dim3(D4 / 64, T / 64), 256, 0, stream>>>(
            H, fc_w + (size_t)l * D4 * D, fc_b + (size_t)l * D4, Mb, T, D4, D);
        // x += m @ proj_w^T + proj_b
        gemm_nt<3><<<dim3(D / 64, T / 64), 256, 0, stream>>>(
            Mb, proj_w + (size_t)l * D * D4, proj_b + (size_t)l * D, X, T, D, D4);
    }

    // hf = LN(x); logits = hf @ wte^T + unemb_b  (fp32 out)
    ln_kernel<<<T, 256, 0, stream>>>(X, lnf_w, H);
    gemm_nt<1><<<dim3(V / 64, T / 64), 256, 0, stream>>>(
        H, wte, unemb_b, out, T, V, D);
}

// Round 3
// 2546.955 us; speedup vs baseline: 3.6559x; 3.6559x over previous
//
#include <hip/hip_runtime.h>
#include <hip/hip_bf16.h>

typedef __bf16 bf16_t;
typedef __bf16 bf16x8 __attribute__((ext_vector_type(8)));
typedef __bf16 bf16x4 __attribute__((ext_vector_type(4)));
typedef float  f32x4  __attribute__((ext_vector_type(4)));

// async global->LDS, 16B per lane. LDS dest = wave-uniform base + lane*16.
__device__ __forceinline__ void gl_lds16(const void* g, void* l) {
    __builtin_amdgcn_global_load_lds(
        (__attribute__((address_space(1))) void*)g,
        (__attribute__((address_space(3))) void*)l, 16, 0, 0);
}

// ---------------------------------------------------------------------------
// fp32 -> bf16 cast, vectorized (n must be multiple of 4)
// ---------------------------------------------------------------------------
__global__ void cvt_kernel(const float* __restrict__ in, bf16_t* __restrict__ out,
                           int n4) {
    const int i = blockIdx.x * 256 + threadIdx.x;
    if (i < n4) {
        const float4 v = ((const float4*)in)[i];
        bf16x4 o;
        o.x = (bf16_t)v.x; o.y = (bf16_t)v.y; o.z = (bf16_t)v.z; o.w = (bf16_t)v.w;
        ((bf16x4*)out)[i] = o;
    }
}

// ---------------------------------------------------------------------------
// Embedding gather: x[t,:] = wte[idx[t],:]  (fp32)
// ---------------------------------------------------------------------------
__global__ void embed_kernel(const int* __restrict__ idx,
                             const float* __restrict__ wte,
                             float* __restrict__ x) {
    const int t = blockIdx.x;
    const int row = idx[t];
    const float* w = wte + (size_t)row * 768;
    float* o = x + (size_t)t * 768;
    for (int d = threadIdx.x; d < 768; d += 256) o[d] = w[d];
}

// ---------------------------------------------------------------------------
// LayerNorm: out(bf16) = (x - mu) * rsqrt(var + eps) * w      D = 768
// ---------------------------------------------------------------------------
__global__ __launch_bounds__(256) void ln_kernel(const float* __restrict__ x,
                                                 const float* __restrict__ w,
                                                 bf16_t* __restrict__ out) {
    const int t = blockIdx.x, tid = threadIdx.x;
    __shared__ float red[256];
    const float* xr = x + (size_t)t * 768;
    const float v0 = xr[tid], v1 = xr[tid + 256], v2 = xr[tid + 512];
    red[tid] = v0 + v1 + v2;
    __syncthreads();
    for (int s = 128; s > 0; s >>= 1) {
        if (tid < s) red[tid] += red[tid + s];
        __syncthreads();
    }
    const float mu = red[0] * (1.0f / 768.0f);
    __syncthreads();
    const float d0 = v0 - mu, d1 = v1 - mu, d2 = v2 - mu;
    red[tid] = d0 * d0 + d1 * d1 + d2 * d2;
    __syncthreads();
    for (int s = 128; s > 0; s >>= 1) {
        if (tid < s) red[tid] += red[tid + s];
        __syncthreads();
    }
    const float rstd = rsqrtf(red[0] * (1.0f / 768.0f) + 1e-5f);
    bf16_t* orow = out + (size_t)t * 768;
    orow[tid]       = (bf16_t)(d0 * rstd * w[tid]);
    orow[tid + 256] = (bf16_t)(d1 * rstd * w[tid + 256]);
    orow[tid + 512] = (bf16_t)(d2 * rstd * w[tid + 512]);
}

// ---------------------------------------------------------------------------
// RoPE in-place on Q and K halves of qkv [T, 2304] fp32.
// ---------------------------------------------------------------------------
__global__ void rope_kernel(float* __restrict__ qkv) {
    const int t = blockIdx.x, h = blockIdx.y;
    const int tid = threadIdx.x;
    const int i = tid & 31;
    const int which = tid >> 5;  // 0 = Q, 1 = K
    float* base = qkv + (size_t)t * 2304 + which * 768 + h * 64;
    const float inv_freq = __powf(10000.0f, -(float)i * (1.0f / 32.0f));
    const float ang = (float)t * inv_freq;
    const float s = sinf(ang), c = cosf(ang);
    const float x1 = base[i], x2 = base[i + 32];
    base[i]      = x1 * c - x2 * s;
    base[i + 32] = x1 * s + x2 * c;
}

// ---------------------------------------------------------------------------
// Flash attention: one block = (64-query tile, head). 256 threads.
// qkv [T,2304] fp32; y [T,768] bf16. Online softmax, O in registers.
// ---------------------------------------------------------------------------
__global__ __launch_bounds__(256) void attn_kernel(const float* __restrict__ qkv,
                                                   bf16_t* __restrict__ y) {
    const int qt = (int)gridDim.x - 1 - (int)blockIdx.x;  // longest blocks first
    const int h  = blockIdx.y;
    const int q0 = qt * 64;
    const int tid = threadIdx.x;

    __shared__ float Qs[64 * 64];      // [d][q] transposed
    __shared__ float Ks[64 * 64];      // [d][k] transposed
    __shared__ float Vs[64 * 64];      // [k][d]
    __shared__ float Ps[64 * 65];      // [q][k], padded rows
    __shared__ float red[256];
    __shared__ float mrow[64], lrow[64], arow[64];

    // load Q tile (transposed) ; thread t -> q = t>>2, d0 = (t&3)*16
    const int lq = tid >> 2, ld0 = (tid & 3) * 16;
    {
        const float* qp = qkv + (size_t)(q0 + lq) * 2304 + h * 64 + ld0;
        #pragma unroll
        for (int c = 0; c < 4; ++c) {
            const float4 v = *(const float4*)(qp + c * 4);
            Qs[(ld0 + c * 4 + 0) * 64 + lq] = v.x;
            Qs[(ld0 + c * 4 + 1) * 64 + lq] = v.y;
            Qs[(ld0 + c * 4 + 2) * 64 + lq] = v.z;
            Qs[(ld0 + c * 4 + 3) * 64 + lq] = v.w;
        }
    }
    if (tid < 64) { mrow[tid] = -3e38f; lrow[tid] = 0.0f; arow[tid] = 0.0f; }
    float o[16];
    #pragma unroll
    for (int i = 0; i < 16; ++i) o[i] = 0.0f;

    const int qg = tid >> 4, kg = tid & 15;   // phase A mapping (4x4 block)
    const int bq = tid >> 2, bs = tid & 3;    // phase B mapping
    const int cq = bq, cd = ld0;              // phase C mapping

    for (int kt = 0; kt <= qt; ++kt) {
        __syncthreads();  // previous tile fully consumed
        // stage K (transposed) and V (natural)
        {
            const float* kp = qkv + (size_t)(kt * 64 + lq) * 2304 + 768 + h * 64 + ld0;
            const float* vp = kp + 768;
            #pragma unroll
            for (int c = 0; c < 4; ++c) {
                const float4 kv = *(const float4*)(kp + c * 4);
                Ks[(ld0 + c * 4 + 0) * 64 + lq] = kv.x;
                Ks[(ld0 + c * 4 + 1) * 64 + lq] = kv.y;
                Ks[(ld0 + c * 4 + 2) * 64 + lq] = kv.z;
                Ks[(ld0 + c * 4 + 3) * 64 + lq] = kv.w;
                *(float4*)(Vs + lq * 64 + ld0 + c * 4) = *(const float4*)(vp + c * 4);
            }
        }
        __syncthreads();

        // phase A: S[q][k] 4x4 micro-tile per thread
        float s[4][4];
        #pragma unroll
        for (int i = 0; i < 4; ++i)
            #pragma unroll
            for (int j = 0; j < 4; ++j) s[i][j] = 0.0f;
        #pragma unroll 8
        for (int d = 0; d < 64; ++d) {
            const float4 qv = *(const float4*)(Qs + d * 64 + qg * 4);
            const float4 kv = *(const float4*)(Ks + d * 64 + kg * 4);
            const float qa[4] = {qv.x, qv.y, qv.z, qv.w};
            const float ka[4] = {kv.x, kv.y, kv.z, kv.w};
            #pragma unroll
            for (int i = 0; i < 4; ++i)
                #pragma unroll
                for (int j = 0; j < 4; ++j) s[i][j] += qa[i] * ka[j];
        }
        const bool diag = (kt == qt);
        #pragma unroll
        for (int i = 0; i < 4; ++i) {
            #pragma unroll
            for (int j = 0; j < 4; ++j) {
                float sv = s[i][j] * 0.125f;
                if (diag && (kg * 4 + j) > (qg * 4 + i)) sv = -3e38f;
                Ps[(qg * 4 + i) * 65 + kg * 4 + j] = sv;
            }
        }
        __syncthreads();

        // phase B: online softmax row update (4 threads per row)
        float lmax = -3e38f;
        #pragma unroll
        for (int i = 0; i < 16; ++i) lmax = fmaxf(lmax, Ps[bq * 65 + bs * 16 + i]);
        red[tid] = lmax;
        __syncthreads();
        if (bs == 0) {
            const float mt = fmaxf(fmaxf(red[bq * 4], red[bq * 4 + 1]),
                                   fmaxf(red[bq * 4 + 2], red[bq * 4 + 3]));
            const float m_new = fmaxf(mrow[bq], mt);
            arow[bq] = __expf(mrow[bq] - m_new);
            mrow[bq] = m_new;
        }
        __syncthreads();
        const float m_new = mrow[bq];
        float lsum = 0.0f;
        #pragma unroll
        for (int i = 0; i < 16; ++i) {
            const float p = __expf(Ps[bq * 65 + bs * 16 + i] - m_new);
            Ps[bq * 65 + bs * 16 + i] = p;
            lsum += p;
        }
        red[tid] = lsum;
        __syncthreads();
        if (bs == 0)
            lrow[bq] = lrow[bq] * arow[bq] +
                       (red[bq * 4] + red[bq * 4 + 1] + red[bq * 4 + 2] + red[bq * 4 + 3]);

        // phase C: O = O*alpha + P @ V
        const float a = arow[cq];
        #pragma unroll
        for (int i = 0; i < 16; ++i) o[i] *= a;
        for (int k = 0; k < 64; ++k) {
            const float p = Ps[cq * 65 + k];
            #pragma unroll
            for (int c = 0; c < 4; ++c) {
                const float4 vv = *(const float4*)(Vs + k * 64 + cd + c * 4);
                o[c * 4 + 0] += p * vv.x;
                o[c * 4 + 1] += p * vv.y;
                o[c * 4 + 2] += p * vv.z;
                o[c * 4 + 3] += p * vv.w;
            }
        }
        __syncthreads();
    }

    const float inv = 1.0f / lrow[cq];
    bf16_t* yo = y + (size_t)(q0 + cq) * 768 + h * 64 + cd;
    #pragma unroll
    for (int i = 0; i < 16; ++i) yo[i] = (bf16_t)(o[i] * inv);
}

// ---------------------------------------------------------------------------
// MFMA NT GEMM: C[M,N] = A[M,K](bf16) * B[N,K](bf16)^T, fp32 accumulate.
// Tile 128x128, BK=32, 256 threads (4 waves, 2x2 of 64x64).
// Staging via global_load_lds width=16. M,N % 128 == 0, K % 32 == 0.
// FLAGS: 1=bias(fp32), 2=residual into C32, 4=exact GELU, 8=bf16 out
// ---------------------------------------------------------------------------
template <int FLAGS>
__global__ __launch_bounds__(256) void gemm_bt(const bf16_t* __restrict__ A,
                                               const bf16_t* __restrict__ B,
                                               const float* __restrict__ bias,
                                               float* __restrict__ C32,
                                               bf16_t* __restrict__ Cb,
                                               int M, int N, int K) {
    constexpr bool HAS_BIAS = (FLAGS & 1) != 0;
    constexpr bool HAS_RES  = (FLAGS & 2) != 0;
    constexpr bool HAS_GELU = (FLAGS & 4) != 0;
    constexpr bool OUT_BF16 = (FLAGS & 8) != 0;

    __shared__ bf16_t As[128 * 32];
    __shared__ bf16_t Bs[128 * 32];

    const int tid = threadIdx.x;
    const int w = tid >> 6, lane = tid & 63;
    const int bm = blockIdx.y * 128, bn = blockIdx.x * 128;
    const int wm = (w >> 1) * 64, wn = (w & 1) * 64;

    // staging: wave w covers tile rows [w*32, w*32+32); lane -> (row, col8)
    const int sr = w * 32 + (lane >> 2);
    const int sc = (lane & 3) * 8;
    const bf16_t* gA0 = A + (size_t)(bm + sr) * K + sc;
    const bf16_t* gA1 = gA0 + (size_t)16 * K;
    const bf16_t* gB0 = B + (size_t)(bn + sr) * K + sc;
    const bf16_t* gB1 = gB0 + (size_t)16 * K;
    bf16_t* lA0 = As + (w * 32) * 32;
    bf16_t* lA1 = As + (w * 32 + 16) * 32;
    bf16_t* lB0 = Bs + (w * 32) * 32;
    bf16_t* lB1 = Bs + (w * 32 + 16) * 32;

    const int mrow  = lane & 15;
    const int khalf = (lane >> 4) * 8;

    f32x4 acc[4][4];
    #pragma unroll
    for (int i = 0; i < 4; ++i)
        #pragma unroll
        for (int j = 0; j < 4; ++j) acc[i][j] = (f32x4)(0.0f);

    for (int k0 = 0; k0 < K; k0 += 32) {
        __syncthreads();
        gl_lds16(gA0 + k0, lA0);
        gl_lds16(gA1 + k0, lA1);
        gl_lds16(gB0 + k0, lB0);
        gl_lds16(gB1 + k0, lB1);
        __syncthreads();
        bf16x8 af[4], bfr[4];
        #pragma unroll
        for (int i = 0; i < 4; ++i)
            af[i] = *(const bf16x8*)(As + (wm + i * 16 + mrow) * 32 + khalf);
        #pragma unroll
        for (int j = 0; j < 4; ++j)
            bfr[j] = *(const bf16x8*)(Bs + (wn + j * 16 + mrow) * 32 + khalf);
        #pragma unroll
        for (int i = 0; i < 4; ++i)
            #pragma unroll
            for (int j = 0; j < 4; ++j)
                acc[i][j] = __builtin_amdgcn_mfma_f32_16x16x32_bf16(
                    af[i], bfr[j], acc[i][j], 0, 0, 0);
    }

    // epilogue: C/D layout col = lane&15, row = (lane>>4)*4 + reg
    const int ccol = lane & 15;
    const int crow = (lane >> 4) * 4;
    #pragma unroll
    for (int i = 0; i < 4; ++i) {
        #pragma unroll
        for (int j = 0; j < 4; ++j) {
            const int col = bn + wn + j * 16 + ccol;
            #pragma unroll
            for (int r = 0; r < 4; ++r) {
                const int row = bm + wm + i * 16 + crow + r;
                float v = acc[i][j][r];
                if constexpr (HAS_BIAS) v += bias[col];
                if constexpr (HAS_GELU) v = 0.5f * v * (1.0f + erff(v * 0.70710678f));
                const size_t off = (size_t)row * N + col;
                if constexpr (HAS_RES) v += C32[off];
                if constexpr (OUT_BF16) Cb[off] = (bf16_t)v;
                else C32[off] = v;
            }
        }
    }
}

// ---------------------------------------------------------------------------
// Host launch
// ---------------------------------------------------------------------------
extern "C" void kernel_launch(void* const* d_in, const int* in_sizes, int n_in,
                              void* d_out, int out_size, void* d_ws, size_t ws_size,
                              hipStream_t stream) {
    const int T = 2048, D = 768, NH = 12, L = 4, V = 32000;
    const int D3 = 3 * D, D4 = 4 * D;

    const int*   idx        = (const int*)d_in[0];
    const float* wte        = (const float*)d_in[1];
    const float* ln1_w      = (const float*)d_in[2];
    const float* attn_w     = (const float*)d_in[3];
    const float* attnproj_w = (const float*)d_in[4];
    const float* ln2_w      = (const float*)d_in[5];
    const float* fc_w       = (const float*)d_in[6];
    const float* fc_b       = (const float*)d_in[7];
    const float* proj_w     = (const float*)d_in[8];
    const float* proj_b     = (const float*)d_in[9];
    const float* lnf_w      = (const float*)d_in[10];
    const float* unemb_b    = (const float*)d_in[11];
    float* out = (float*)d_out;

    // workspace layout (~91.6 MB)
    char* p = (char*)d_ws;
    float*  X      = (float*)p;   p += (size_t)T * D * 4;        // 6.29 MB
    bf16_t* Hb     = (bf16_t*)p;  p += (size_t)T * D * 2;        // 3.15 MB
    float*  QKV    = (float*)p;                                   // 18.9 MB
    bf16_t* Mb     = (bf16_t*)p;  p += (size_t)T * D3 * 4;       // (union, QKV larger)
    bf16_t* wte_b  = (bf16_t*)p;  p += (size_t)V * D * 2;        // 49.2 MB
    bf16_t* w_attn = (bf16_t*)p;  p += (size_t)D3 * D * 2;
    bf16_t* w_apr  = (bf16_t*)p;  p += (size_t)D * D * 2;
    bf16_t* w_fc   = (bf16_t*)p;  p += (size_t)D4 * D * 2;
    bf16_t* w_proj = (bf16_t*)p;  p += (size_t)D * D4 * 2;

    embed_kernel<<<T, 256, 0, stream>>>(idx, wte, X);
    {
        const int n4 = V * D / 4;
        cvt_kernel<<<(n4 + 255) / 256, 256, 0, stream>>>(wte, wte_b, n4);
    }

    for (int l = 0; l < L; ++l) {
        // per-layer weight casts (fp32 -> bf16)
        int n4;
        n4 = D3 * D / 4;
        cvt_kernel<<<(n4 + 255) / 256, 256, 0, stream>>>(attn_w + (size_t)l * D3 * D, w_attn, n4);
        n4 = D * D / 4;
        cvt_kernel<<<(n4 + 255) / 256, 256, 0, stream>>>(attnproj_w + (size_t)l * D * D, w_apr, n4);
        n4 = D4 * D / 4;
        cvt_kernel<<<(n4 + 255) / 256, 256, 0, stream>>>(fc_w + (size_t)l * D4 * D, w_fc, n4);
        n4 = D * D4 / 4;
        cvt_kernel<<<(n4 + 255) / 256, 256, 0, stream>>>(proj_w + (size_t)l * D * D4, w_proj, n4);

        // h = LN1(x)  (bf16)
        ln_kernel<<<T, 256, 0, stream>>>(X, ln1_w + (size_t)l * D, Hb);
        // qkv = h @ attn_w^T  (fp32 out)
        gemm_bt<0><<<dim3(D3 / 128, T / 128), 256, 0, stream>>>(
            Hb, w_attn, nullptr, QKV, nullptr, T, D3, D);
        // RoPE
        rope_kernel<<<dim3(T, NH), 64, 0, stream>>>(QKV);
        // y = attn(qkv)  (bf16 into Hb)
        attn_kernel<<<dim3(T / 64, NH), 256, 0, stream>>>(QKV, Hb);
        // x += y @ attnproj_w^T
        gemm_bt<2><<<dim3(D / 128, T / 128), 256, 0, stream>>>(
            Hb, w_apr, nullptr, X, nullptr, T, D, D);
        // h = LN2(x)
        ln_kernel<<<T, 256, 0, stream>>>(X, ln2_w + (size_t)l * D, Hb);
        // m = gelu(h @ fc_w^T + fc_b)  (bf16 out)
        gemm_bt<13><<<dim3(D4 / 128, T / 128), 256, 0, stream>>>(
            Hb, w_fc, fc_b + (size_t)l * D4, nullptr, Mb, T, D4, D);
        // x += m @ proj_w^T + proj_b
        gemm_bt<3><<<dim3(D / 128, T / 128), 256, 0, stream>>>(
            Mb, w_proj, proj_b + (size_t)l * D, X, nullptr, T, D, D4);
    }

    // hf = LN(x); logits = hf @ wte^T + unemb_b  (fp32 out)
    ln_kernel<<<T, 256, 0, stream>>>(X, lnf_w, Hb);
    gemm_bt<1><<<dim3(V / 128, T / 128), 256, 0, stream>>>(
        Hb, wte_b, unemb_b, out, nullptr, T, V, D);
}